// Round 1
// 250.267 us; speedup vs baseline: 1.0069x; 1.0069x over previous
//
#include <hip/hip_runtime.h>
#include <stdint.h>

// ---------------------------------------------------------------------------
// SelfAttention: q,k,v = hs@W.T+b ; E = exp(q@k.T) (no max-sub needed: |logit|<~60)
// l = rowsum(E); context = (E@Vt)*(1/l); scores_j = sum_q E[q,j]/l_q
// R11: logits rebuilt on 256x256 deep-pipelined core (T2+T3+T4+T5):
//   512 thr / 8 waves (2Mx4N, 128x64 each), BK=32, 4-slot LDS ring (128KB),
//   counted vmcnt(8) once per K-tile (never 0 in loop), raw s_barrier pairs,
//   setprio(1) around 16-MFMA clusters, 2-bit XOR chunk swizzle, XCD-swizzled
//   blockIdx. Grid (8,8,4)=256 blocks = exactly 1/CU.
//   proj/context stay on the verified 128x128 core (R6 best: 249.8us) until
//   the 256-tile core is harness-verified; they get BM/BN variants next.
// ws layout: q[0..16M) k[16..32M) vt[32..48M) l@48M(32K) part@48M+128K(1MB)
//   {hsb[49..65M) Wb[65..71M)} | E[49..81M) aliased.  Requires ws >= 81MB.
// ---------------------------------------------------------------------------

typedef __attribute__((ext_vector_type(8))) short short8;
typedef __attribute__((ext_vector_type(4))) float floatx4;
typedef __attribute__((ext_vector_type(4))) unsigned short ushort4v;
typedef unsigned short u16;

__device__ __forceinline__ u16 f2bf(float f) {
  union { float f; uint32_t u; } v; v.f = f;
  uint32_t u = v.u;
  return (u16)((u + 0x7FFFu + ((u >> 16) & 1u)) >> 16);  // RNE
}
__device__ __forceinline__ float bf2f(u16 h) {
  union { uint32_t u; float f; } v; v.u = ((uint32_t)h) << 16; return v.f;
}

#define AS3(p) ((__attribute__((address_space(3))) void*)(uint32_t)(uintptr_t)(p))
#define AS1(p) ((__attribute__((address_space(1))) void*)(uintptr_t)(p))

// ---------------------------------------------------------------------------
// Fused convert: hs (8192 blocks) + Wq/Wk/Wv (3*1024 blocks); block 0 also
// zeroes lsum (needed by logits' atomics).
__global__ __launch_bounds__(256) void cvt_all_kernel(
    const float* __restrict__ hs, const float* __restrict__ Wq,
    const float* __restrict__ Wk, const float* __restrict__ Wv,
    u16* __restrict__ hsb, u16* __restrict__ Wb, float* __restrict__ lsum) {
  const int bx = blockIdx.x;
  const float* src;
  u16* dst;
  int i;
  if (bx < 8192) {
    i = bx * 1024 + threadIdx.x * 4;
    src = hs; dst = hsb;
  } else {
    const int idx = bx - 8192;
    const int p = idx >> 10, blk = idx & 1023;
    src = (p == 0) ? Wq : (p == 1) ? Wk : Wv;
    dst = Wb + p * 1048576;
    i = blk * 1024 + threadIdx.x * 4;
  }
  const float4 v = *(const float4*)(src + i);
  ushort4v o;
  o[0] = f2bf(v.x); o[1] = f2bf(v.y); o[2] = f2bf(v.z); o[3] = f2bf(v.w);
  *(ushort4v*)(dst + i) = o;
  if (bx == 0) {
    float4 z = {0.f, 0.f, 0.f, 0.f};
#pragma unroll
    for (int k = 0; k < 8; ++k)
      *(float4*)(lsum + threadIdx.x * 32 + k * 4) = z;
  }
}

// ---------------------------------------------------------------------------
// core bt-GEMM (verified R6): C[128,128] += A[128,K] * B[128,K]^T
// block = 256 thr = 4 waves (2x2), each wave 64x64 = 4x4 frags of 16x16x32.
__device__ __forceinline__ void gemm_core(const u16* __restrict__ A,
                                          const u16* __restrict__ B,
                                          int lda, int ldb, int K,
                                          u16* As, u16* Bs, floatx4 acc[4][4]) {
  const int tid  = threadIdx.x;
  const int lane = tid & 63;
  const int w    = tid >> 6;
  const int wr   = (w >> 1) * 64;      // wave row base (m)
  const int wc   = (w & 1) * 64;       // wave col base (n)
  const int fr   = lane & 15;          // frag row within 16
  const int quad = lane >> 4;          // 0..3 -> k-chunk within 32-K half

  const u16* pa[4];
  const u16* pb[4];
#pragma unroll
  for (int j = 0; j < 4; ++j) {
    const int q   = tid + j * 256;
    const int row = q >> 3, col = q & 7;
    const int gc  = col ^ (row & 7);
    pa[j] = A + row * lda + gc * 8;
    pb[j] = B + row * ldb + gc * 8;
  }

  for (int kk = 0; kk < K; kk += 64) {
#pragma unroll
    for (int j = 0; j < 4; ++j) {
      __builtin_amdgcn_global_load_lds(AS1(pa[j]), AS3(As + (tid + j * 256) * 8), 16, 0, 0);
      __builtin_amdgcn_global_load_lds(AS1(pb[j]), AS3(Bs + (tid + j * 256) * 8), 16, 0, 0);
      pa[j] += 64; pb[j] += 64;
    }
    __syncthreads();
#pragma unroll
    for (int ks = 0; ks < 2; ++ks) {
      const int pc = ((ks * 4 + quad) ^ (fr & 7)) * 8;
      short8 af[4], bfr[4];
#pragma unroll
      for (int i = 0; i < 4; ++i) {
        af[i]  = *(const short8*)(As + (wr + i * 16 + fr) * 64 + pc);
        bfr[i] = *(const short8*)(Bs + (wc + i * 16 + fr) * 64 + pc);
      }
#pragma unroll
      for (int mi = 0; mi < 4; ++mi)
#pragma unroll
        for (int ni = 0; ni < 4; ++ni)
          acc[mi][ni] = __builtin_amdgcn_mfma_f32_16x16x32_bf16(af[mi], bfr[ni],
                                                                acc[mi][ni], 0, 0, 0);
    }
    __syncthreads();
  }
}

// ---------------------------------------------------------------------------
// K1: q/k/v projections.  C = hs @ W.T + b.  p=0:q  p=1:k  p=2: v stored transposed.
__global__ __launch_bounds__(256, 3) void proj_kernel(
    const u16* __restrict__ hsb, const u16* __restrict__ Wb,
    const float* __restrict__ bq, const float* __restrict__ bk,
    const float* __restrict__ bv,
    u16* __restrict__ qo, u16* __restrict__ ko, u16* __restrict__ vt) {
  __shared__ __align__(16) u16 As[8192];
  __shared__ __align__(16) u16 Bs[8192];
  floatx4 acc[4][4];
#pragma unroll
  for (int i = 0; i < 4; ++i)
#pragma unroll
    for (int j = 0; j < 4; ++j) acc[i][j] = {0.f, 0.f, 0.f, 0.f};

  const int p  = blockIdx.z;
  const int m0 = blockIdx.x * 128;
  const int n0 = blockIdx.y * 128;
  gemm_core(hsb + m0 * 1024, Wb + p * 1048576 + n0 * 1024, 1024, 1024, 1024, As, Bs, acc);

  const float* bias = (p == 0) ? bq : (p == 1) ? bk : bv;
  const int lane = threadIdx.x & 63, w = threadIdx.x >> 6;
  const int wr = (w >> 1) * 64, wc = (w & 1) * 64;
  const int col = lane & 15, rg4 = (lane >> 4) * 4;

  if (p < 2) {
    u16* out = (p == 0) ? qo : ko;
#pragma unroll
    for (int mi = 0; mi < 4; ++mi)
#pragma unroll
      for (int ni = 0; ni < 4; ++ni) {
        const int n = n0 + wc + ni * 16 + col;
        const float bn = bias[n];
#pragma unroll
        for (int r = 0; r < 4; ++r) {
          const int m = m0 + wr + mi * 16 + rg4 + r;
          out[m * 1024 + n] = f2bf(acc[mi][ni][r] + bn);
        }
      }
  } else {
#pragma unroll
    for (int mi = 0; mi < 4; ++mi) {
      const int mbase = m0 + wr + mi * 16 + rg4;
      const int b = mbase >> 11, s = mbase & 2047;
#pragma unroll
      for (int ni = 0; ni < 4; ++ni) {
        const int n = n0 + wc + ni * 16 + col;
        const float bn = bias[n];
        ushort4v pk;
#pragma unroll
        for (int r = 0; r < 4; ++r) pk[r] = f2bf(acc[mi][ni][r] + bn);
        *(ushort4v*)(vt + b * 2097152 + n * 2048 + s) = pk;
      }
    }
  }
}

// ---------------------------------------------------------------------------
// K2 (R11): E = exp(q @ k.T) (bf16), l = rowsum(E) via shfl-reduce + atomics.
// 256x256 tile, BK=32, 4-slot LDS ring, counted vmcnt(8), 2x 16-MFMA phases
// per K-tile with setprio, 2-bit XOR chunk swizzle. 512 thr, dynamic LDS 128KB.
#define LG_SLOT 16384  // u16 per ring slot: A 8192 (256x32) + B 8192

__global__ __launch_bounds__(512, 2) void logits256_kernel(
    const u16* __restrict__ q, const u16* __restrict__ k,
    u16* __restrict__ E, float* __restrict__ lsum) {
  extern __shared__ __align__(16) u16 smem[];

  const int tid  = threadIdx.x;
  const int lane = tid & 63;
  const int w    = tid >> 6;
  const int wm   = w >> 2;            // 0..1  (M half)
  const int wn   = w & 3;             // 0..3  (N quarter)
  const int fr   = lane & 15;
  const int quad = lane >> 4;
  const int pc   = (quad ^ (fr & 3)) * 8;   // swizzled k-chunk (elems)

  // bijective XCD swizzle over 256 blocks: each XCD gets 32 contiguous ids
  const int flat = blockIdx.x + (blockIdx.y << 3) + (blockIdx.z << 6);
  const int swz  = ((flat & 7) << 5) | (flat >> 3);
  const int b    = swz >> 6;
  const int m0   = ((swz >> 3) & 7) << 8;   // query tile base
  const int n0   = (swz & 7) << 8;          // key tile base

  const u16* Ag = q + (b * 2048 + m0) * 1024;
  const u16* Bg = k + (b * 2048 + n0) * 1024;

  // staging: per tile 4 loads/thread (A j=0,1 ; B j=0,1), 16B each.
  // LDS linear chunk c = tid + j*512 -> (row=c>>2, kc=c&3); content = global
  // chunk kc ^ (row&3)  (inverse-swizzled source, swizzled ds_read).
  const u16* pA[2]; const u16* pB[2];
  uint32_t dA[2], dB[2];
#pragma unroll
  for (int j = 0; j < 2; ++j) {
    const int c   = tid + j * 512;
    const int row = c >> 2, kc = c & 3;
    const int gc  = kc ^ (row & 3);
    pA[j] = Ag + row * 1024 + gc * 8;
    pB[j] = Bg + row * 1024 + gc * 8;
    dA[j] = j * 4096 + tid * 8;
    dB[j] = 8192 + j * 4096 + tid * 8;
  }

#define LG_STAGE_A(u) do { u16* sb_ = smem + ((u) & 3) * LG_SLOT;                         \
    __builtin_amdgcn_global_load_lds(AS1(pA[0] + (u) * 32), AS3(sb_ + dA[0]), 16, 0, 0);  \
    __builtin_amdgcn_global_load_lds(AS1(pA[1] + (u) * 32), AS3(sb_ + dA[1]), 16, 0, 0); } while (0)
#define LG_STAGE_B(u) do { u16* sb_ = smem + ((u) & 3) * LG_SLOT;                         \
    __builtin_amdgcn_global_load_lds(AS1(pB[0] + (u) * 32), AS3(sb_ + dB[0]), 16, 0, 0);  \
    __builtin_amdgcn_global_load_lds(AS1(pB[1] + (u) * 32), AS3(sb_ + dB[1]), 16, 0, 0); } while (0)

  floatx4 acc[8][4];
#pragma unroll
  for (int i = 0; i < 8; ++i)
#pragma unroll
    for (int j = 0; j < 4; ++j) acc[i][j] = {0.f, 0.f, 0.f, 0.f};

  // prologue: tiles 0,1,2 (12 vmem instr); wait tile 0 (oldest 4) landed
  LG_STAGE_A(0); LG_STAGE_B(0);
  LG_STAGE_A(1); LG_STAGE_B(1);
  LG_STAGE_A(2); LG_STAGE_B(2);
  asm volatile("s_waitcnt vmcnt(8)" ::: "memory");
  __builtin_amdgcn_s_barrier();

  const int arow0 = wm * 128 + fr;    // + h*64 + mi*16
  const int brow0 = wn * 64 + fr;     // + ni*16

#pragma unroll 4
  for (int t = 0; t < 32; ++t) {
    const u16* sA = smem + (t & 3) * LG_SLOT;
    const u16* sB = sA + 8192;
    short8 bf[4], af[4];

    // ---- phase 0: ds_read B(all ni) + A(mi 0-3); stage A(t+3); MFMA mi0-3
#pragma unroll
    for (int ni = 0; ni < 4; ++ni)
      bf[ni] = *(const short8*)(sB + (brow0 + ni * 16) * 32 + pc);
#pragma unroll
    for (int mi = 0; mi < 4; ++mi)
      af[mi] = *(const short8*)(sA + (arow0 + mi * 16) * 32 + pc);
    if (t < 29) LG_STAGE_A(t + 3);
    __builtin_amdgcn_s_barrier();
    asm volatile("s_waitcnt lgkmcnt(0)" ::: "memory");
    __builtin_amdgcn_sched_barrier(0);
    __builtin_amdgcn_s_setprio(1);
#pragma unroll
    for (int mi = 0; mi < 4; ++mi)
#pragma unroll
      for (int ni = 0; ni < 4; ++ni)
        acc[mi][ni] = __builtin_amdgcn_mfma_f32_16x16x32_bf16(af[mi], bf[ni],
                                                              acc[mi][ni], 0, 0, 0);
    __builtin_amdgcn_s_setprio(0);
    __builtin_amdgcn_s_barrier();

    // ---- phase 1: ds_read A(mi 4-7); stage B(t+3); vmcnt(8); MFMA mi4-7
#pragma unroll
    for (int mi = 0; mi < 4; ++mi)
      af[mi] = *(const short8*)(sA + (arow0 + 64 + mi * 16) * 32 + pc);
    if (t < 29) LG_STAGE_B(t + 3);
    // once per K-tile: everything older than the last 8 vmem instrs (tiles
    // t-1,t staging) has landed -> tile t+1's slot is ready. Never 0.
    asm volatile("s_waitcnt vmcnt(8)" ::: "memory");
    __builtin_amdgcn_s_barrier();
    asm volatile("s_waitcnt lgkmcnt(0)" ::: "memory");
    __builtin_amdgcn_sched_barrier(0);
    __builtin_amdgcn_s_setprio(1);
#pragma unroll
    for (int mi = 0; mi < 4; ++mi)
#pragma unroll
      for (int ni = 0; ni < 4; ++ni)
        acc[mi + 4][ni] = __builtin_amdgcn_mfma_f32_16x16x32_bf16(af[mi], bf[ni],
                                                                  acc[mi + 4][ni], 0, 0, 0);
    __builtin_amdgcn_s_setprio(0);
    __builtin_amdgcn_s_barrier();
  }

  // ---- epilogue: exp, E store, rowsum via 16-lane shfl + atomics
  u16* Eb = E + b * 4194304;
  float* lb = lsum + b * 2048;
  const int colw = n0 + wn * 64 + fr;
#pragma unroll
  for (int mi = 0; mi < 8; ++mi) {
    floatx4 rs = {0.f, 0.f, 0.f, 0.f};
    const int rbase = m0 + wm * 128 + mi * 16 + quad * 4;
#pragma unroll
    for (int ni = 0; ni < 4; ++ni) {
      const int n = colw + ni * 16;
#pragma unroll
      for (int r = 0; r < 4; ++r) {
        const float e = __expf(acc[mi][ni][r]);
        rs[r] += e;
        Eb[(rbase + r) * 2048 + n] = f2bf(e);
      }
    }
#pragma unroll
    for (int off = 1; off < 16; off <<= 1) {
      rs[0] += __shfl_xor(rs[0], off, 64);
      rs[1] += __shfl_xor(rs[1], off, 64);
      rs[2] += __shfl_xor(rs[2], off, 64);
      rs[3] += __shfl_xor(rs[3], off, 64);
    }
    if (fr == 0) {
#pragma unroll
      for (int r = 0; r < 4; ++r) atomicAdd(&lb[rbase + r], rs[r]);
    }
  }
}

// ---------------------------------------------------------------------------
// K4: context = (E @ Vt) * (1/l)   -> d_out fp32
__global__ __launch_bounds__(256, 3) void context_kernel(
    const u16* __restrict__ E, const u16* __restrict__ vt,
    const float* __restrict__ lsum, float* __restrict__ out) {
  __shared__ __align__(16) u16 As[8192];
  __shared__ __align__(16) u16 Bs[8192];
  floatx4 acc[4][4];
#pragma unroll
  for (int i = 0; i < 4; ++i)
#pragma unroll
    for (int j = 0; j < 4; ++j) acc[i][j] = {0.f, 0.f, 0.f, 0.f};

  const int b  = blockIdx.z;
  const int m0 = blockIdx.y * 128;   // query tile
  const int n0 = blockIdx.x * 128;   // h tile
  gemm_core(E + b * 4194304 + m0 * 2048, vt + b * 2097152 + n0 * 2048,
            2048, 2048, 2048, As, Bs, acc);

  const int lane = threadIdx.x & 63, w = threadIdx.x >> 6;
  const int wr = (w >> 1) * 64, wc = (w & 1) * 64;
  const int col = lane & 15, rg4 = (lane >> 4) * 4;
  const float* lb = lsum + b * 2048;

#pragma unroll
  for (int mi = 0; mi < 4; ++mi) {
    const int rbase = m0 + wr + mi * 16 + rg4;
    float rinv[4];
#pragma unroll
    for (int r = 0; r < 4; ++r) rinv[r] = 1.0f / lb[rbase + r];
#pragma unroll
    for (int ni = 0; ni < 4; ++ni) {
      const int n = n0 + wc + ni * 16 + col;
#pragma unroll
      for (int r = 0; r < 4; ++r)
        out[(b * 2048 + rbase + r) * 1024 + n] = acc[mi][ni][r] * rinv[r];
    }
  }
}

// ---------------------------------------------------------------------------
// K3a: partial column sums: part[b][g][j] = sum_{q in rows g*64..+64} E[q,j]/l_q
__global__ __launch_bounds__(256) void colsum_part_kernel(
    const u16* __restrict__ E, const float* __restrict__ lsum,
    float* __restrict__ part) {
  const int b  = blockIdx.x;
  const int g  = blockIdx.y;
  const int q0 = g * 64;
  const int j  = threadIdx.x * 8;
  const u16* Eb = E + b * 4194304;
  const float* lb = lsum + b * 2048;
  float acc[8];
#pragma unroll
  for (int c = 0; c < 8; ++c) acc[c] = 0.f;
  for (int r = 0; r < 64; ++r) {
    const int qi = q0 + r;
    const float rinv = 1.0f / lb[qi];
    const short8 ev = *(const short8*)(Eb + qi * 2048 + j);
#pragma unroll
    for (int c = 0; c < 8; ++c) acc[c] += bf2f((u16)ev[c]) * rinv;
  }
  float* pb = part + (b * 32 + g) * 2048 + j;
#pragma unroll
  for (int c = 0; c < 8; ++c) pb[c] = acc[c];
}

// K3b: scores[b][j] = sum_g part[b][g][j]
__global__ __launch_bounds__(256) void colsum_reduce_kernel(
    const float* __restrict__ part, float* __restrict__ scores) {
  const int b = blockIdx.x;
  const int j = blockIdx.y * 256 + threadIdx.x;
  const float* pb = part + b * 32 * 2048 + j;
  float s = 0.f;
#pragma unroll
  for (int g = 0; g < 32; ++g) s += pb[g * 2048];
  scores[b * 2048 + j] = s;
}

// ---------------------------------------------------------------------------
extern "C" void kernel_launch(void* const* d_in, const int* in_sizes, int n_in,
                              void* d_out, int out_size, void* d_ws, size_t ws_size,
                              hipStream_t stream) {
  const float* hs = (const float*)d_in[0];
  const float* Wq = (const float*)d_in[1];
  const float* bq = (const float*)d_in[2];
  const float* Wk = (const float*)d_in[3];
  const float* bk = (const float*)d_in[4];
  const float* Wv = (const float*)d_in[5];
  const float* bv = (const float*)d_in[6];

  char* ws = (char*)d_ws;
  u16*   qw  = (u16*)(ws);                                // 16 MB
  u16*   kw  = (u16*)(ws + (16u << 20));                  // 16 MB
  u16*   vtw = (u16*)(ws + (32u << 20));                  // 16 MB
  float* lw  = (float*)(ws + (48u << 20));                // 32 KB
  float* pw  = (float*)(ws + (48u << 20) + (128u << 10)); // 1 MB partials
  u16*   hsb = (u16*)(ws + (49u << 20));                  // 16 MB (dead after proj)
  u16*   Wb  = (u16*)(ws + (65u << 20));                  // 6 MB  (dead after proj)
  u16*   Ew  = (u16*)(ws + (49u << 20));                  // 32 MB (aliases hsb/Wb)

  float* outc = (float*)d_out;           // context [4,2048,1024]
  float* outs = outc + 8388608;          // scores  [4,2048]

  static int s_attr_done = 0;
  if (!s_attr_done) {
    (void)hipFuncSetAttribute((const void*)logits256_kernel,
                              hipFuncAttributeMaxDynamicSharedMemorySize, 131072);
    s_attr_done = 1;
  }

  cvt_all_kernel<<<11264, 256, 0, stream>>>(hs, Wq, Wk, Wv, hsb, Wb, lw);
  proj_kernel<<<dim3(64, 8, 3), 256, 0, stream>>>(hsb, Wb, bq, bk, bv, qw, kw, vtw);
  logits256_kernel<<<dim3(8, 8, 4), 512, 131072, stream>>>(qw, kw, Ew, lw);
  context_kernel<<<dim3(8, 16, 4), 256, 0, stream>>>(Ew, vtw, lw, outc);
  colsum_part_kernel<<<dim3(4, 32), 256, 0, stream>>>(Ew, lw, pw);
  colsum_reduce_kernel<<<dim3(4, 8), 256, 0, stream>>>(pw, outs);
}

// Round 2
// 241.414 us; speedup vs baseline: 1.0438x; 1.0367x over previous
//
#include <hip/hip_runtime.h>
#include <stdint.h>

// ---------------------------------------------------------------------------
// SelfAttention: q,k,v = hs@W.T+b ; E = exp(q@k.T) (no max-sub needed: |logit|<~60)
// l = rowsum(E); context = (E@Vt)*(1/l); scores_j = sum_q E[q,j]/l_q
// R12: ONE deep-pipelined core for all three GEMMs.
//   BM=256 BN=128 BK=64, 512 thr / 8 waves (4Mx2N, 64x64/wave, acc[4][4]),
//   3-slot LDS ring (3x48KB=144KB), stage t+2 during t, counted vmcnt(6)
//   once per K-tile (drain only at tail), 2 phases x 16 MFMA w/ setprio,
//   R6's verified conflict-free 8-chunk XOR swizzle (BK=64 -> 3-bit XOR; the
//   R11 BK=32 2-bit XOR left a 4-way ds_read conflict = the T2 gate).
//   Grids all perfect CU multiples: proj 768=3 passes, logits 512=2,
//   context 256=1. Bijective chunked XCD swizzle per grid.
// ws layout: q[0..16M) k[16..32M) vt[32..48M) l@48M(32K) part@48M+128K(1MB)
//   {hsb[49..65M) Wb[65..71M)} | E[49..81M) aliased.  Requires ws >= 81MB.
// ---------------------------------------------------------------------------

typedef __attribute__((ext_vector_type(8))) short short8;
typedef __attribute__((ext_vector_type(4))) float floatx4;
typedef __attribute__((ext_vector_type(4))) unsigned short ushort4v;
typedef unsigned short u16;

__device__ __forceinline__ u16 f2bf(float f) {
  union { float f; uint32_t u; } v; v.f = f;
  uint32_t u = v.u;
  return (u16)((u + 0x7FFFu + ((u >> 16) & 1u)) >> 16);  // RNE
}
__device__ __forceinline__ float bf2f(u16 h) {
  union { uint32_t u; float f; } v; v.u = ((uint32_t)h) << 16; return v.f;
}

#define AS3(p) ((__attribute__((address_space(3))) void*)(uint32_t)(uintptr_t)(p))
#define AS1(p) ((__attribute__((address_space(1))) void*)(uintptr_t)(p))

// ---------------------------------------------------------------------------
// Fused convert: hs (8192 blocks) + Wq/Wk/Wv (3*1024 blocks); block 0 also
// zeroes lsum (needed by logits' atomics).
__global__ __launch_bounds__(256) void cvt_all_kernel(
    const float* __restrict__ hs, const float* __restrict__ Wq,
    const float* __restrict__ Wk, const float* __restrict__ Wv,
    u16* __restrict__ hsb, u16* __restrict__ Wb, float* __restrict__ lsum) {
  const int bx = blockIdx.x;
  const float* src;
  u16* dst;
  int i;
  if (bx < 8192) {
    i = bx * 1024 + threadIdx.x * 4;
    src = hs; dst = hsb;
  } else {
    const int idx = bx - 8192;
    const int p = idx >> 10, blk = idx & 1023;
    src = (p == 0) ? Wq : (p == 1) ? Wk : Wv;
    dst = Wb + p * 1048576;
    i = blk * 1024 + threadIdx.x * 4;
  }
  const float4 v = *(const float4*)(src + i);
  ushort4v o;
  o[0] = f2bf(v.x); o[1] = f2bf(v.y); o[2] = f2bf(v.z); o[3] = f2bf(v.w);
  *(ushort4v*)(dst + i) = o;
  if (bx == 0) {
    float4 z = {0.f, 0.f, 0.f, 0.f};
#pragma unroll
    for (int k = 0; k < 8; ++k)
      *(float4*)(lsum + threadIdx.x * 32 + k * 4) = z;
  }
}

// ---------------------------------------------------------------------------
// Deep-pipelined bt-GEMM core: C[256,128] += A[256,K] * B[128,K]^T
// 512 thr / 8 waves (4Mx2N). K-tile 64. LDS slot: A 256x64 (32KB) + B 128x64
// (16KB) = 24576 u16; ring of 3. Per K-tile: 6 global_load_lds/thread
// (A 4, B 2), 16 ds_read_b128/thread, 32 MFMA/thread over 2 phases.
// Swizzle: LDS chunk (row, kc) holds global chunk kc ^ (row&7) (16B chunks);
// ds_read at chunk ((ks*4+quad) ^ (fr&7)) — conflict-free (R6-verified).
#define DC_SLOT 24576

template <int NT>
__device__ __forceinline__ void deep_core(const u16* __restrict__ A,
                                          const u16* __restrict__ B,
                                          int lda, int ldb,
                                          u16* smem, floatx4 acc[4][4]) {
  const int tid  = threadIdx.x;
  const int lane = tid & 63;
  const int w    = tid >> 6;
  const int wm   = w >> 1;            // 0..3  (M quarter, 64 rows)
  const int wn   = w & 1;             // 0..1  (N half, 64 cols)
  const int fr   = lane & 15;
  const int quad = lane >> 4;
  const int pc0  = (quad ^ (fr & 7)) * 8;
  const int pc1  = ((4 + quad) ^ (fr & 7)) * 8;

  const u16* pA[4]; uint32_t dA[4];
#pragma unroll
  for (int j = 0; j < 4; ++j) {
    const int c = tid + j * 512, row = c >> 3, kc = c & 7;
    pA[j] = A + row * lda + (kc ^ (row & 7)) * 8;
    dA[j] = c * 8;
  }
  const u16* pB[2]; uint32_t dB[2];
#pragma unroll
  for (int j = 0; j < 2; ++j) {
    const int c = tid + j * 512, row = c >> 3, kc = c & 7;
    pB[j] = B + row * ldb + (kc ^ (row & 7)) * 8;
    dB[j] = 16384 + c * 8;
  }

#define DC_STA(u) do { u16* s_ = smem + ((u) % 3) * DC_SLOT;                                  \
    _Pragma("unroll") for (int j_ = 0; j_ < 4; ++j_)                                           \
      __builtin_amdgcn_global_load_lds(AS1(pA[j_] + (u) * 64), AS3(s_ + dA[j_]), 16, 0, 0);   \
  } while (0)
#define DC_STB(u) do { u16* s_ = smem + ((u) % 3) * DC_SLOT;                                  \
    _Pragma("unroll") for (int j_ = 0; j_ < 2; ++j_)                                           \
      __builtin_amdgcn_global_load_lds(AS1(pB[j_] + (u) * 64), AS3(s_ + dB[j_]), 16, 0, 0);   \
  } while (0)

  // prologue: tiles 0,1 (12 loads); wait tile 0 (oldest 6)
  DC_STA(0); DC_STB(0); DC_STA(1); DC_STB(1);
  asm volatile("s_waitcnt vmcnt(6)" ::: "memory");
  __builtin_amdgcn_s_barrier();

  const int arow0 = wm * 64 + fr;
  const int brow0 = wn * 64 + fr;

#pragma unroll
  for (int t = 0; t < NT; ++t) {
    const u16* sA = smem + (t % 3) * DC_SLOT;
    const u16* sB = sA + 16384;
    short8 af[4], bf[4];

    // ---- phase 0 (ks=0): 8 ds_read; stage A(t+2); 16 MFMA
#pragma unroll
    for (int mi = 0; mi < 4; ++mi)
      af[mi] = *(const short8*)(sA + (arow0 + mi * 16) * 64 + pc0);
#pragma unroll
    for (int ni = 0; ni < 4; ++ni)
      bf[ni] = *(const short8*)(sB + (brow0 + ni * 16) * 64 + pc0);
    if (t < NT - 2) DC_STA(t + 2);
    __builtin_amdgcn_s_barrier();
    asm volatile("s_waitcnt lgkmcnt(0)" ::: "memory");
    __builtin_amdgcn_sched_barrier(0);
    __builtin_amdgcn_s_setprio(1);
#pragma unroll
    for (int mi = 0; mi < 4; ++mi)
#pragma unroll
      for (int ni = 0; ni < 4; ++ni)
        acc[mi][ni] = __builtin_amdgcn_mfma_f32_16x16x32_bf16(af[mi], bf[ni],
                                                              acc[mi][ni], 0, 0, 0);
    __builtin_amdgcn_s_setprio(0);
    __builtin_amdgcn_s_barrier();

    // ---- phase 1 (ks=1): 8 ds_read; stage B(t+2); counted vmcnt(6); 16 MFMA
#pragma unroll
    for (int mi = 0; mi < 4; ++mi)
      af[mi] = *(const short8*)(sA + (arow0 + mi * 16) * 64 + pc1);
#pragma unroll
    for (int ni = 0; ni < 4; ++ni)
      bf[ni] = *(const short8*)(sB + (brow0 + ni * 16) * 64 + pc1);
    if (t < NT - 2) {
      DC_STB(t + 2);
      // outstanding: tile t+1 (6) + tile t+2 (6); wait tile t+1 landed.
      asm volatile("s_waitcnt vmcnt(6)" ::: "memory");
    } else {
      asm volatile("s_waitcnt vmcnt(0)" ::: "memory");  // tail drain only
    }
    __builtin_amdgcn_s_barrier();
    asm volatile("s_waitcnt lgkmcnt(0)" ::: "memory");
    __builtin_amdgcn_sched_barrier(0);
    __builtin_amdgcn_s_setprio(1);
#pragma unroll
    for (int mi = 0; mi < 4; ++mi)
#pragma unroll
      for (int ni = 0; ni < 4; ++ni)
        acc[mi][ni] = __builtin_amdgcn_mfma_f32_16x16x32_bf16(af[mi], bf[ni],
                                                              acc[mi][ni], 0, 0, 0);
    __builtin_amdgcn_s_setprio(0);
    __builtin_amdgcn_s_barrier();
  }
#undef DC_STA
#undef DC_STB
}

// ---------------------------------------------------------------------------
// K1: q/k/v projections.  C = hs @ W.T + b.  p=0:q  p=1:k  p=2: v transposed.
// grid (8,32,3) = 768 blocks = 3 perfect passes of 256.
__global__ __launch_bounds__(512, 2) void proj_deep_kernel(
    const u16* __restrict__ hsb, const u16* __restrict__ Wb,
    const float* __restrict__ bq, const float* __restrict__ bk,
    const float* __restrict__ bv,
    u16* __restrict__ qo, u16* __restrict__ ko, u16* __restrict__ vt) {
  extern __shared__ __align__(16) u16 smem[];
  floatx4 acc[4][4];
#pragma unroll
  for (int i = 0; i < 4; ++i)
#pragma unroll
    for (int j = 0; j < 4; ++j) acc[i][j] = {0.f, 0.f, 0.f, 0.f};

  const int p    = blockIdx.z;
  const int flat = blockIdx.x + blockIdx.y * 8;          // 0..255 per pass
  const int swz  = (flat & 7) * 32 + (flat >> 3);        // bijective XCD chunk
  const int m0   = (swz >> 3) * 256;
  const int n0   = (swz & 7) * 128;

  deep_core<16>(hsb + m0 * 1024, Wb + p * 1048576 + n0 * 1024, 1024, 1024, smem, acc);

  const float* bias = (p == 0) ? bq : (p == 1) ? bk : bv;
  const int lane = threadIdx.x & 63, w = threadIdx.x >> 6;
  const int wm = w >> 1, wn = w & 1;
  const int fr = lane & 15, rg4 = (lane >> 4) * 4;

  if (p < 2) {
    u16* out = (p == 0) ? qo : ko;
#pragma unroll
    for (int mi = 0; mi < 4; ++mi)
#pragma unroll
      for (int ni = 0; ni < 4; ++ni) {
        const int n = n0 + wn * 64 + ni * 16 + fr;
        const float bn = bias[n];
#pragma unroll
        for (int r = 0; r < 4; ++r) {
          const int m = m0 + wm * 64 + mi * 16 + rg4 + r;
          out[m * 1024 + n] = f2bf(acc[mi][ni][r] + bn);
        }
      }
  } else {
    // v transposed: vt[b][h][s], 4 consecutive s per lane -> 8B packed store
#pragma unroll
    for (int mi = 0; mi < 4; ++mi) {
      const int mbase = m0 + wm * 64 + mi * 16 + rg4;
      const int b = mbase >> 11, s = mbase & 2047;
#pragma unroll
      for (int ni = 0; ni < 4; ++ni) {
        const int n = n0 + wn * 64 + ni * 16 + fr;
        const float bn = bias[n];
        ushort4v pk;
#pragma unroll
        for (int r = 0; r < 4; ++r) pk[r] = f2bf(acc[mi][ni][r] + bn);
        *(ushort4v*)(vt + b * 2097152 + n * 2048 + s) = pk;
      }
    }
  }
}

// ---------------------------------------------------------------------------
// K2: E = exp(q @ k.T) (bf16), l = rowsum(E) via 16-lane shfl + atomics.
// grid (16,8,4) = 512 blocks = 2 perfect passes.
__global__ __launch_bounds__(512, 2) void logits_deep_kernel(
    const u16* __restrict__ q, const u16* __restrict__ k,
    u16* __restrict__ E, float* __restrict__ lsum) {
  extern __shared__ __align__(16) u16 smem[];
  floatx4 acc[4][4];
#pragma unroll
  for (int i = 0; i < 4; ++i)
#pragma unroll
    for (int j = 0; j < 4; ++j) acc[i][j] = {0.f, 0.f, 0.f, 0.f};

  const int flat = blockIdx.x + blockIdx.y * 16 + blockIdx.z * 128;  // 0..511
  const int swz  = (flat & 7) * 64 + (flat >> 3);
  const int b    = swz >> 7;
  const int m0   = ((swz >> 4) & 7) * 256;   // query tile base
  const int n0   = (swz & 15) * 128;         // key tile base

  deep_core<16>(q + (b * 2048 + m0) * 1024, k + (b * 2048 + n0) * 1024,
                1024, 1024, smem, acc);

  const int lane = threadIdx.x & 63, w = threadIdx.x >> 6;
  const int wm = w >> 1, wn = w & 1;
  const int fr = lane & 15, quad = lane >> 4;
  u16* Eb = E + b * 4194304;
  float* lb = lsum + b * 2048;

#pragma unroll
  for (int mi = 0; mi < 4; ++mi) {
    floatx4 rs = {0.f, 0.f, 0.f, 0.f};
    const int rbase = m0 + wm * 64 + mi * 16 + quad * 4;
#pragma unroll
    for (int ni = 0; ni < 4; ++ni) {
      const int n = n0 + wn * 64 + ni * 16 + fr;
#pragma unroll
      for (int r = 0; r < 4; ++r) {
        const float e = __expf(acc[mi][ni][r]);
        rs[r] += e;
        Eb[(rbase + r) * 2048 + n] = f2bf(e);
      }
    }
#pragma unroll
    for (int off = 1; off < 16; off <<= 1) {
      rs[0] += __shfl_xor(rs[0], off, 64);
      rs[1] += __shfl_xor(rs[1], off, 64);
      rs[2] += __shfl_xor(rs[2], off, 64);
      rs[3] += __shfl_xor(rs[3], off, 64);
    }
    if (fr == 0) {
#pragma unroll
      for (int r = 0; r < 4; ++r) atomicAdd(&lb[rbase + r], rs[r]);
    }
  }
}

// ---------------------------------------------------------------------------
// K4: context = (E @ Vt) * (1/l) -> d_out fp32. grid (8,8,4) = 256 = 1 pass.
__global__ __launch_bounds__(512, 2) void context_deep_kernel(
    const u16* __restrict__ E, const u16* __restrict__ vt,
    const float* __restrict__ lsum, float* __restrict__ out) {
  extern __shared__ __align__(16) u16 smem[];
  floatx4 acc[4][4];
#pragma unroll
  for (int i = 0; i < 4; ++i)
#pragma unroll
    for (int j = 0; j < 4; ++j) acc[i][j] = {0.f, 0.f, 0.f, 0.f};

  const int flat = blockIdx.x + blockIdx.y * 8 + blockIdx.z * 64;  // 0..255
  const int swz  = (flat & 7) * 32 + (flat >> 3);
  const int b    = swz >> 6;
  const int m0   = ((swz >> 3) & 7) * 256;   // query tile
  const int n0   = (swz & 7) * 128;          // h tile

  deep_core<32>(E + b * 4194304 + m0 * 2048, vt + b * 2097152 + n0 * 2048,
                2048, 2048, smem, acc);

  const int lane = threadIdx.x & 63, w = threadIdx.x >> 6;
  const int wm = w >> 1, wn = w & 1;
  const int fr = lane & 15, rg4 = (lane >> 4) * 4;
  const float* lb = lsum + b * 2048;

#pragma unroll
  for (int mi = 0; mi < 4; ++mi) {
    const int rbase = m0 + wm * 64 + mi * 16 + rg4;
    float rinv[4];
#pragma unroll
    for (int r = 0; r < 4; ++r) rinv[r] = 1.0f / lb[rbase + r];
#pragma unroll
    for (int ni = 0; ni < 4; ++ni) {
      const int n = n0 + wn * 64 + ni * 16 + fr;
#pragma unroll
      for (int r = 0; r < 4; ++r)
        out[(b * 2048 + rbase + r) * 1024 + n] = acc[mi][ni][r] * rinv[r];
    }
  }
}

// ---------------------------------------------------------------------------
// K3a: partial column sums: part[b][g][j] = sum_{q in rows g*64..+64} E[q,j]/l_q
__global__ __launch_bounds__(256) void colsum_part_kernel(
    const u16* __restrict__ E, const float* __restrict__ lsum,
    float* __restrict__ part) {
  const int b  = blockIdx.x;
  const int g  = blockIdx.y;
  const int q0 = g * 64;
  const int j  = threadIdx.x * 8;
  const u16* Eb = E + b * 4194304;
  const float* lb = lsum + b * 2048;
  float acc[8];
#pragma unroll
  for (int c = 0; c < 8; ++c) acc[c] = 0.f;
  for (int r = 0; r < 64; ++r) {
    const int qi = q0 + r;
    const float rinv = 1.0f / lb[qi];
    const short8 ev = *(const short8*)(Eb + qi * 2048 + j);
#pragma unroll
    for (int c = 0; c < 8; ++c) acc[c] += bf2f((u16)ev[c]) * rinv;
  }
  float* pb = part + (b * 32 + g) * 2048 + j;
#pragma unroll
  for (int c = 0; c < 8; ++c) pb[c] = acc[c];
}

// K3b: scores[b][j] = sum_g part[b][g][j]
__global__ __launch_bounds__(256) void colsum_reduce_kernel(
    const float* __restrict__ part, float* __restrict__ scores) {
  const int b = blockIdx.x;
  const int j = blockIdx.y * 256 + threadIdx.x;
  const float* pb = part + b * 32 * 2048 + j;
  float s = 0.f;
#pragma unroll
  for (int g = 0; g < 32; ++g) s += pb[g * 2048];
  scores[b * 2048 + j] = s;
}

// ---------------------------------------------------------------------------
extern "C" void kernel_launch(void* const* d_in, const int* in_sizes, int n_in,
                              void* d_out, int out_size, void* d_ws, size_t ws_size,
                              hipStream_t stream) {
  const float* hs = (const float*)d_in[0];
  const float* Wq = (const float*)d_in[1];
  const float* bq = (const float*)d_in[2];
  const float* Wk = (const float*)d_in[3];
  const float* bk = (const float*)d_in[4];
  const float* Wv = (const float*)d_in[5];
  const float* bv = (const float*)d_in[6];

  char* ws = (char*)d_ws;
  u16*   qw  = (u16*)(ws);                                // 16 MB
  u16*   kw  = (u16*)(ws + (16u << 20));                  // 16 MB
  u16*   vtw = (u16*)(ws + (32u << 20));                  // 16 MB
  float* lw  = (float*)(ws + (48u << 20));                // 32 KB
  float* pw  = (float*)(ws + (48u << 20) + (128u << 10)); // 1 MB partials
  u16*   hsb = (u16*)(ws + (49u << 20));                  // 16 MB (dead after proj)
  u16*   Wb  = (u16*)(ws + (65u << 20));                  // 6 MB  (dead after proj)
  u16*   Ew  = (u16*)(ws + (49u << 20));                  // 32 MB (aliases hsb/Wb)

  float* outc = (float*)d_out;           // context [4,2048,1024]
  float* outs = outc + 8388608;          // scores  [4,2048]

  static int s_attr_done = 0;
  if (!s_attr_done) {
    (void)hipFuncSetAttribute((const void*)proj_deep_kernel,
                              hipFuncAttributeMaxDynamicSharedMemorySize, 147456);
    (void)hipFuncSetAttribute((const void*)logits_deep_kernel,
                              hipFuncAttributeMaxDynamicSharedMemorySize, 147456);
    (void)hipFuncSetAttribute((const void*)context_deep_kernel,
                              hipFuncAttributeMaxDynamicSharedMemorySize, 147456);
    s_attr_done = 1;
  }

  cvt_all_kernel<<<11264, 256, 0, stream>>>(hs, Wq, Wk, Wv, hsb, Wb, lw);
  proj_deep_kernel<<<dim3(8, 32, 3), 512, 147456, stream>>>(hsb, Wb, bq, bk, bv, qw, kw, vtw);
  logits_deep_kernel<<<dim3(16, 8, 4), 512, 147456, stream>>>(qw, kw, Ew, lw);
  context_deep_kernel<<<dim3(8, 8, 4), 512, 147456, stream>>>(Ew, vtw, lw, outc);
  colsum_part_kernel<<<dim3(4, 32), 256, 0, stream>>>(Ew, lw, pw);
  colsum_reduce_kernel<<<dim3(4, 8), 256, 0, stream>>>(pw, outs);
}